// Round 11
// baseline (95.060 us; speedup 1.0000x reference)
//
#include <hip/hip_runtime.h>
#include <stdint.h>

// iSTFT as fused bf16-MFMA GEMM + overlap-add, with even/odd frequency fold.
//   frames[m][n]     = win[n]     * (E[m][n] + O[m][n])      n in [0,256)
//   frames[m][n+256] = win[n+256] * (E[m][n] - O[m][n])
//   E = even f (K=258, 9 steps of 32), O = odd f (K=256, 8 steps)
// R11: occupancy via SMALLER PER-WAVE TILE. R10 post-mortem: occupancy never
// rose because acc (64 f32) sits in AGPRs -> 64 VGPR + 64 AGPR = 128/thread
// -> 4 waves/SIMD cap; LDS was irrelevant. Here: block = 4 waves (256 thr),
// per-wave tile M=16 x foldedN=64, acc = 32 f32, q depth-2 = 16, af 4
// -> ~80 unified regs -> 6 waves/SIMD possible; LDS = 32768 B exactly
// (B dbuf 2x16KB + 18KB pitch-36 epilogue aliased) -> 5 blocks/CU
// = 20 waves/CU (62%) and 5 independent 4-wave barrier domains (was 2x8).
// Sync skeleton unchanged from R7/R9/R10 (raw s_barrier + counted vmcnt,
// B via global_load_lds, A direct->reg): per step issue B(ks+1) then
// A(ks+2); steady wait vmcnt(4) (= A(ks+1) in flight), last step vmcnt(0).
// Prologue order B0,A0,A1 makes the ladder uniform.

#define EPS_F 1.1920928955078125e-07f
#define TWO_PI_OVER_512 1.2271846303085130e-02f

typedef __bf16 bf16x8 __attribute__((ext_vector_type(8)));
typedef float f32x4 __attribute__((ext_vector_type(4)));

__device__ __forceinline__ uint16_t f2bf_bits(float x) {
  return __builtin_bit_cast(uint16_t, (__bf16)x);
}
__device__ __forceinline__ float bf2f_bits(uint16_t u) {
  return (float)__builtin_bit_cast(__bf16, u);
}

#define GLOAD16(srcp, dstp)                                                   \
  __builtin_amdgcn_global_load_lds(                                          \
      (const __attribute__((address_space(1))) uint32_t*)(srcp),             \
      (__attribute__((address_space(3))) uint32_t*)(dstp), 16, 0, 0)

// Table: 544 rows x N=256 bf16. Rows 0..287 = even-f phase (k_e = 2*fe+c,
// f = 2*fe, fe<=128 valid, rest zero-pad); rows 288..543 = odd-f phase
// (k_o = 2*fo+c, f = 2*fo+1). Packed 16B units: unit u = (k>>3)*256 + n,
// byte = (u<<4 ^ ((g&3)<<5)) + (k&7)*2  (bank swizzle baked into global
// layout so global_load_lds tile copies are verbatim).
__global__ void build_table_kernel(uint8_t* __restrict__ tb) {
  const int k = blockIdx.x;        // 0..543
  const int g = k >> 3;
  const int n = threadIdx.x;       // 0..255
  float v = 0.0f;
  int f, c, valid;
  if (k < 288) {
    const int fe = k >> 1;
    c = k & 1; f = 2 * fe; valid = (fe <= 128);
  } else {
    const int ko = k - 288;
    c = ko & 1; f = 2 * (ko >> 1) + 1; valid = 1;
  }
  if (valid) {
    const float s = (f == 0 || f == 256) ? 1.0f : 2.0f;
    const int a = (f * n) & 511;   // exact angle reduction
    const float th = (float)a * TWO_PI_OVER_512;
    const float tr = c ? -sinf(th) : cosf(th);
    v = s * tr * (1.0f / 512.0f);
  }
  const int off = (((g * 256 + n) << 4) ^ ((g & 3) << 5)) + ((k & 7) << 1);
  *(uint16_t*)(tb + off) = f2bf_bits(v);
}

// epilogue frame buffer: 512 cols x 16 rows bf16, pitch 36B (9 dwords, odd
// -> consecutive cols spread across all banks; <=2-way everywhere).
__device__ __forceinline__ float rd_sf(const uint8_t* sF, int col, int row) {
  return bf2f_bits(*(const uint16_t*)(sF + col * 36 + row * 2));
}

// One block: batch b, 16 frames [t0, t0+16), t0 = ib*15 (1-frame halo);
// ib==266 overlaps back to t0=3984. Owns chunks t0+1..t0+15 (ib==266: only
// 3991..3999) + chunk 0 on ib==0, chunk 4000 on ib==266.
__global__ __launch_bounds__(256, 5)
void istft_fused_kernel(const float2* __restrict__ in,   // [B*257*4000] (re,im)
                        const float* __restrict__ win,   // [512]
                        const uint8_t* __restrict__ tb,  // packed table
                        float* __restrict__ out) {
  __shared__ __align__(1024) uint8_t smem[32768];
  uint8_t* sB = smem;   // 2 x 16KB B double-buffer (K-loop)
  uint8_t* sF = smem;   // epilogue alias: 512 cols x 36B = 18432B

  const int tid  = threadIdx.x;
  const int lane = tid & 63;
  const int wave = tid >> 6;       // 0..3 = N-quarter of the folded 256
  const int l15  = lane & 15;
  const int g    = lane >> 4;      // k-group within fragment
  const int b  = blockIdx.y;
  const int ib = blockIdx.x;       // 0..266
  const int t0 = (ib == 266) ? 3984 : ib * 15;

  f32x4 accE[4], accO[4];
#pragma unroll
  for (int nj = 0; nj < 4; ++nj) {
    accE[nj] = (f32x4){0.f, 0.f, 0.f, 0.f};
    accO[nj] = (f32x4){0.f, 0.f, 0.f, 0.f};
  }

  const long inBase = (long)b * (257L * 4000);
  const long tcol   = inBase + (t0 + l15);   // + f*4000

  float2 q[2][4];  // A ping-pong: q[ks&1][p]

  // step KS (compile-time under full unroll):
  //   KS<9  even phase: fe = KS*16+g*4+p (clamp 128; B rows beyond are 0)
  //   KS>=9 odd  phase: f = 2*((KS-9)*16+g*4+p)+1
#define ISSUE_A(KS)                                                           \
  {                                                                           \
    float2* qd = q[(KS) & 1];                                                 \
    _Pragma("unroll") for (int p = 0; p < 4; ++p) {                           \
      int f;                                                                  \
      if ((KS) < 9) {                                                         \
        int fe = (KS) * 16 + g * 4 + p;                                       \
        if (fe > 128) fe = 128;                                               \
        f = 2 * fe;                                                           \
      } else {                                                                \
        f = 2 * (((KS) - 9) * 16 + g * 4 + p) + 1;                            \
      }                                                                       \
      qd[p] = in[tcol + (long)f * 4000];                                      \
    }                                                                         \
  }
#define ISSUE_B(T)                                                            \
  {                                                                           \
    const uint8_t* src = tb + (T) * 16384 + wave * 4096 + lane * 16;          \
    uint8_t* dst = sB + ((T) & 1) * 16384 + wave * 4096 + lane * 16;          \
    _Pragma("unroll") for (int c = 0; c < 4; ++c)                             \
      GLOAD16(src + c * 1024, dst + c * 1024);                                \
  }

  // ---- prologue: B0(4), A0(4), A1(4) — order IS the vmcnt contract ----
  ISSUE_B(0);
  __builtin_amdgcn_sched_barrier(0);
  ISSUE_A(0);
  __builtin_amdgcn_sched_barrier(0);
  ISSUE_A(1);
  __builtin_amdgcn_sched_barrier(0);

  const int nbase = ((g * 256 + wave * 64 + l15) << 4) ^ (g << 5);

#pragma unroll
  for (int ks = 0; ks < 17; ++ks) {
    // retire through {A(ks), B(ks)}; keep A(ks+1) (4 loads) in flight
    if (ks < 16)
      asm volatile("s_waitcnt vmcnt(4)" ::: "memory");
    else
      asm volatile("s_waitcnt vmcnt(0)" ::: "memory");
    __builtin_amdgcn_s_barrier();   // buf[ks&1] published; step ks-1 readers
                                    // of buf[(ks+1)&1] finished before this
    __builtin_amdgcn_sched_barrier(0);

    // ---- B(ks+1) into buf[(ks+1)&1] immediately (max slack, WAR-safe) ----
    if (ks < 16) {
      ISSUE_B(ks + 1);
    }
    __builtin_amdgcn_sched_barrier(0);

    // ---- A fragment from q[ks&1] (k_local = g*8 + 2p + c) ----
    bf16x8 af;
#pragma unroll
    for (int p = 0; p < 4; ++p) {
      const float2 v = q[ks & 1][p];
      af[2 * p]     = (__bf16)v.x;
      af[2 * p + 1] = (__bf16)v.y;
    }
    __builtin_amdgcn_sched_barrier(0);
    // ---- A(ks+2) into q[ks&1] (slots just consumed) ----
    if (ks < 15) {
      ISSUE_A(ks + 2);
    }
    __builtin_amdgcn_sched_barrier(0);

    // ---- B fragments from LDS + 4 MFMA into phase accumulator ----
    const uint8_t* sBc = sB + (ks & 1) * 16384;
    if (ks < 9) {
#pragma unroll
      for (int nj = 0; nj < 4; ++nj) {
        const bf16x8 bfr = *(const bf16x8*)(sBc + nbase + (nj << 8));
        accE[nj] = __builtin_amdgcn_mfma_f32_16x16x32_bf16(af, bfr,
                                                           accE[nj], 0, 0, 0);
      }
    } else {
#pragma unroll
      for (int nj = 0; nj < 4; ++nj) {
        const bf16x8 bfr = *(const bf16x8*)(sBc + nbase + (nj << 8));
        accO[nj] = __builtin_amdgcn_mfma_f32_16x16x32_bf16(af, bfr,
                                                           accO[nj], 0, 0, 0);
      }
    }
  }

  // ---- epilogue: combine E/O, window, stage 16 frames, OLA ----
  __syncthreads();  // all K-loop LDS reads done; smem becomes sF
  float* outb = out + (long)b * 1024256;
  const float invd = 1.0f / (1.0f + EPS_F);

#pragma unroll
  for (int nj = 0; nj < 4; ++nj) {
    const int colL = wave * 64 + nj * 16 + l15;
    const int colR = colL + 256;
    const float wl = win[colL];
    const float wr = win[colR];
    const f32x4 e = accE[nj];
    const f32x4 o = accO[nj];
    // D rows = g*4 + reg; pitch-36 rows are 2B apart -> 2 dword writes
    uint32_t lo = (uint32_t)f2bf_bits((e[0] + o[0]) * wl) |
                  ((uint32_t)f2bf_bits((e[1] + o[1]) * wl) << 16);
    uint32_t hi = (uint32_t)f2bf_bits((e[2] + o[2]) * wl) |
                  ((uint32_t)f2bf_bits((e[3] + o[3]) * wl) << 16);
    *(uint32_t*)(sF + colL * 36 + g * 8)     = lo;
    *(uint32_t*)(sF + colL * 36 + g * 8 + 4) = hi;
    lo = (uint32_t)f2bf_bits((e[0] - o[0]) * wr) |
         ((uint32_t)f2bf_bits((e[1] - o[1]) * wr) << 16);
    hi = (uint32_t)f2bf_bits((e[2] - o[2]) * wr) |
         ((uint32_t)f2bf_bits((e[3] - o[3]) * wr) << 16);
    *(uint32_t*)(sF + colR * 36 + g * 8)     = lo;
    *(uint32_t*)(sF + colR * 36 + g * 8 + 4) = hi;
  }
  __syncthreads();

  // OLA chunks 1..15: out[t0+cl][r] = (F[cl-1][256+r] + F[cl][r]) / (1+eps)
  const int r = tid;               // 256 threads = 256 samples
  const int clmin = (ib == 266) ? 7 : 1;   // ib266 owns only 3991..3999
#pragma unroll 1
  for (int cl = clmin; cl <= 15; ++cl) {
    const float v0 = rd_sf(sF, 256 + r, cl - 1);
    const float v1 = rd_sf(sF, r, cl);
    outb[(t0 + cl) * 256 + r] = (v0 + v1) * invd;
  }
  if (ib == 0) {    // chunk 0: frame 0 lower half, denorm = win[r]^2
    const float w = win[r];
    outb[r] = rd_sf(sF, r, 0) / (w * w + EPS_F);
  }
  if (ib == 266) {  // chunk 4000: frame 3999 upper half, denorm = win[256+r]^2
    const float w = win[256 + r];
    outb[1024000 + r] = rd_sf(sF, 256 + r, 15) / (w * w + EPS_F);
  }
}

extern "C" void kernel_launch(void* const* d_in, const int* in_sizes, int n_in,
                              void* d_out, int out_size, void* d_ws, size_t ws_size,
                              hipStream_t stream) {
  (void)in_sizes; (void)n_in; (void)out_size; (void)ws_size;
  const float2* tr = (const float2*)d_in[0];
  const float* win = (const float*)d_in[1];
  uint8_t* tb = (uint8_t*)d_ws;  // 68 * 256 * 16 = 278528 bytes
  build_table_kernel<<<dim3(544), dim3(256), 0, stream>>>(tb);
  istft_fused_kernel<<<dim3(267, 16), dim3(256), 0, stream>>>(tr, win, tb,
                                                              (float*)d_out);
}

// Round 12
// 56.785 us; speedup vs baseline: 1.6740x; 1.6740x over previous
//
#include <hip/hip_runtime.h>
#include <stdint.h>

// iSTFT as fused bf16-MFMA GEMM + overlap-add, with even/odd frequency fold.
//   frames[m][n]     = win[n]     * (E[m][n] + O[m][n])      n in [0,256)
//   frames[m][n+256] = win[n+256] * (E[m][n] - O[m][n])
//   E = even f (K=258 -> 9 steps of 32), O = odd f (K=256 -> 8 steps)
// R12: give the A (HBM) stream real pipeline slack. Evidence: occupancy is
// hard-capped at 4 waves/SIMD by the unified VGPR+AGPR file (R10/R11 both
// measured ~40% regardless of LDS/arch-VGPR), B-depth is exonerated (R9
// flat), so the plateau must be A-side latency/issue. Changes vs R10:
//  - A staged by ONE global_load_lds_dwordx4 per wave per step (was 8 loose
//    8B loads): step A-tile = [16 f][64 t] float2 in LDS; dest offset for
//    lane l is exactly tid*16 (fi=2w+(l>>5), tpair=l&31), satisfying the
//    linear-dest rule. f32 -> bf16 cvt moves into the step (VALU was 17%).
//  - A ring 4 x 8KB -> THREE steps of slack (was 2); WAR safe: slot ks&3 is
//    rewritten by A(ks+4), issued after barrier ks+1, when step-ks readers
//    have retired their ds_reads (MFMA use forces lgkm before the barrier).
//  - ISSUE_B fixed to 2 gloads/wave (old code double-wrote every byte).
//  - vmcnt ladder (issue order per step: B(ks+1) then A(ks+3); prologue
//    A0,A1,B0,A2): wait retires through B(ks); newer = A(ks+2..) -> steady
//    vmcnt(1) for ks<15, vmcnt(0) for ks>=15.
// VMEM instrs per wave-step: 12 -> 3. LDS 64KB (A ring 32 + B dbuf 32, sF
// 36KB aliased) -> 2 blocks/CU unchanged. Regs ~99 -> same 4 waves/SIMD.

#define EPS_F 1.1920928955078125e-07f
#define TWO_PI_OVER_512 1.2271846303085130e-02f

typedef __bf16 bf16x8 __attribute__((ext_vector_type(8)));
typedef float f32x4 __attribute__((ext_vector_type(4)));

__device__ __forceinline__ uint16_t f2bf_bits(float x) {
  return __builtin_bit_cast(uint16_t, (__bf16)x);
}
__device__ __forceinline__ float bf2f_bits(uint16_t u) {
  return (float)__builtin_bit_cast(__bf16, u);
}

#define GLOAD16(srcp, dstp)                                                   \
  __builtin_amdgcn_global_load_lds(                                          \
      (const __attribute__((address_space(1))) uint32_t*)(srcp),             \
      (__attribute__((address_space(3))) uint32_t*)(dstp), 16, 0, 0)

// Table: 544 rows x N=256 bf16. Rows 0..287 = even-f phase (k_e = 2*fe+c,
// f = 2*fe, fe<=128 valid, rest zero-pad); rows 288..543 = odd-f phase
// (k_o = 2*fo+c, f = 2*fo+1). Packed 16B units: unit u = (k>>3)*256 + n,
// byte = (u<<4 ^ ((g&3)<<5)) + (k&7)*2  (bank swizzle baked into global
// layout so global_load_lds tile copies are verbatim).
__global__ void build_table_kernel(uint8_t* __restrict__ tb) {
  const int k = blockIdx.x;        // 0..543
  const int g = k >> 3;
  const int n = threadIdx.x;       // 0..255
  float v = 0.0f;
  int f, c, valid;
  if (k < 288) {
    const int fe = k >> 1;
    c = k & 1; f = 2 * fe; valid = (fe <= 128);
  } else {
    const int ko = k - 288;
    c = ko & 1; f = 2 * (ko >> 1) + 1; valid = 1;
  }
  if (valid) {
    const float s = (f == 0 || f == 256) ? 1.0f : 2.0f;
    const int a = (f * n) & 511;   // exact angle reduction
    const float th = (float)a * TWO_PI_OVER_512;
    const float tr = c ? -sinf(th) : cosf(th);
    v = s * tr * (1.0f / 512.0f);
  }
  const int off = (((g * 256 + n) << 4) ^ ((g & 3) << 5)) + ((k & 7) << 1);
  *(uint16_t*)(tb + off) = f2bf_bits(v);
}

// epilogue frame buffer: 512 cols x 32 rows bf16, pitch 72B, swizzled
__device__ __forceinline__ float rd_sf(const uint8_t* sF, int col, int row2) {
  return bf2f_bits(*(const uint16_t*)(
      sF + col * 72 + ((row2 * 2) ^ (((col >> 4) & 3) << 2))));
}

// One block: batch b, 64 consecutive frames [t0, t0+64), full N=512.
// Owns output chunks [t0+1, t0+63] (+ chunk 0 / chunk 4000 at the ends).
__global__ __launch_bounds__(512, 4)
void istft_fused_kernel(const float2* __restrict__ in,   // [B*257*4000] (re,im)
                        const float* __restrict__ win,   // [512]
                        const uint8_t* __restrict__ tb,  // packed table
                        float* __restrict__ out) {
  __shared__ __align__(1024) uint8_t smem[65536];
  uint8_t* sA = smem;            // A ring: 4 x 8KB, step tile [16 f][64 t] f32x2
  uint8_t* sB = smem + 32768;    // B double-buffer: 2 x 16KB
  uint8_t* sF = smem;            // epilogue alias: 512 cols x 72B

  const int tid  = threadIdx.x;
  const int lane = tid & 63;
  const int wave = tid >> 6;       // 0..7
  const int wn   = wave & 3;       // N-quarter of the folded 256
  const int wm   = wave >> 2;      // M-half
  const int l15  = lane & 15;
  const int g    = lane >> 4;      // k-group within fragment
  const int b  = blockIdx.y;
  const int ib = blockIdx.x;       // 0..63
  const int t0 = (ib == 63) ? 3936 : ib * 63;

  f32x4 accE[2][4], accO[2][4];
#pragma unroll
  for (int mi = 0; mi < 2; ++mi)
#pragma unroll
    for (int nj = 0; nj < 4; ++nj) {
      accE[mi][nj] = (f32x4){0.f, 0.f, 0.f, 0.f};
      accO[mi][nj] = (f32x4){0.f, 0.f, 0.f, 0.f};
    }

  const long inBase = (long)b * (257L * 4000);
  const int fi_me = 2 * wave + (lane >> 5);   // f-index this lane stages
  const int tp_me = 2 * (lane & 31);          // t-pair this lane stages

  // step KS (compile-time under full unroll):
  //   KS<9  even phase: fe = KS*16+fi (clamp 128; table rows beyond are 0)
  //   KS>=9 odd  phase: f = 2*((KS-9)*16+fi)+1
#define ISSUE_A(KS)                                                           \
  {                                                                           \
    int f;                                                                    \
    if ((KS) < 9) {                                                           \
      int fe = (KS) * 16 + fi_me;                                             \
      if (fe > 128) fe = 128;                                                 \
      f = 2 * fe;                                                             \
    } else {                                                                  \
      f = 2 * (((KS) - 9) * 16 + fi_me) + 1;                                  \
    }                                                                         \
    GLOAD16(in + inBase + (long)f * 4000 + (t0 + tp_me),                      \
            sA + ((KS) & 3) * 8192 + tid * 16);                               \
  }
#define ISSUE_B(T)                                                            \
  {                                                                           \
    const uint8_t* src = tb + (T) * 16384 + wave * 2048 + lane * 16;          \
    uint8_t* dst = sB + ((T) & 1) * 16384 + wave * 2048 + lane * 16;          \
    GLOAD16(src, dst);                                                        \
    GLOAD16(src + 1024, dst + 1024);                                          \
  }
#define MFMA_STEP(ACC)                                                        \
  _Pragma("unroll") for (int nj = 0; nj < 4; ++nj) {                          \
    const bf16x8 bfr = *(const bf16x8*)(sBc + nbase + (nj << 8));             \
    ACC[0][nj] = __builtin_amdgcn_mfma_f32_16x16x32_bf16(af[0], bfr,          \
                                                         ACC[0][nj], 0, 0, 0);\
    ACC[1][nj] = __builtin_amdgcn_mfma_f32_16x16x32_bf16(af[1], bfr,          \
                                                         ACC[1][nj], 0, 0, 0);\
  }

  // ---- prologue: A0, A1, B0, A2 — order IS the vmcnt contract ----
  ISSUE_A(0);
  __builtin_amdgcn_sched_barrier(0);
  ISSUE_A(1);
  __builtin_amdgcn_sched_barrier(0);
  ISSUE_B(0);
  __builtin_amdgcn_sched_barrier(0);
  ISSUE_A(2);
  __builtin_amdgcn_sched_barrier(0);

  const int nbase = ((g * 256 + wn * 64 + l15) << 4) ^ (g << 5);

#pragma unroll
  for (int ks = 0; ks < 17; ++ks) {
    // retire through B(ks) (and A(ks+1), older in queue); keep A(ks+2..)
    if (ks < 15)
      asm volatile("s_waitcnt vmcnt(1)" ::: "memory");
    else
      asm volatile("s_waitcnt vmcnt(0)" ::: "memory");
    __builtin_amdgcn_s_barrier();   // sA[ks&3], sB[ks&1] published
    __builtin_amdgcn_sched_barrier(0);

    // ---- refill: B(ks+1) into buf[(ks+1)&1]; A(ks+3) into ring ----
    if (ks < 16) {
      ISSUE_B(ks + 1);
    }
    __builtin_amdgcn_sched_barrier(0);
    if (ks < 14) {
      ISSUE_A(ks + 3);
    }
    __builtin_amdgcn_sched_barrier(0);

    // ---- A fragments from sA[ks&3] ([16 f][64 t] f32 pairs) + cvt ----
    const uint8_t* sAc = sA + (ks & 3) * 8192;
    bf16x8 af[2];
#pragma unroll
    for (int mi = 0; mi < 2; ++mi) {
      const int t = wm * 32 + mi * 16 + l15;
      bf16x8 a;
#pragma unroll
      for (int p = 0; p < 4; ++p) {
        const float2 v =
            *(const float2*)(sAc + (((g * 4 + p) * 64) + t) * 8);
        a[2 * p]     = (__bf16)v.x;   // k_local = g*8 + 2p + 0
        a[2 * p + 1] = (__bf16)v.y;   // k_local = g*8 + 2p + 1
      }
      af[mi] = a;
    }

    // ---- B fragments from LDS + 8 MFMA into phase accumulator ----
    const uint8_t* sBc = sB + (ks & 1) * 16384;
    if (ks < 9) {
      MFMA_STEP(accE);
    } else {
      MFMA_STEP(accO);
    }
  }

  // ---- epilogue: two 32-frame passes through the 36KB swizzled buffer ----
  __syncthreads();  // all K-loop LDS reads done; smem becomes sF
  float* outb = out + (long)b * 1024256;
  const float invd = 1.0f / (1.0f + EPS_F);

  float wL[4], wR[4];
#pragma unroll
  for (int nj = 0; nj < 4; ++nj) {
    wL[nj] = win[wn * 64 + nj * 16 + l15];
    wR[nj] = win[wn * 64 + nj * 16 + l15 + 256];
  }

#define STAGE_PASS()                                                          \
  {                                                                           \
    _Pragma("unroll")                                                         \
    for (int mi = 0; mi < 2; ++mi) {                                          \
      const int q4 = mi * 16 + (g << 2); /* D row=(lane>>4)*4+r */            \
      _Pragma("unroll")                                                       \
      for (int nj = 0; nj < 4; ++nj) {                                        \
        const int colL = wn * 64 + nj * 16 + l15;                             \
        const int colR = colL + 256;                                          \
        const int swzL = ((colL >> 4) & 3) << 2;                              \
        const int swzR = ((colR >> 4) & 3) << 2;                              \
        const f32x4 e = accE[mi][nj];                                         \
        const f32x4 o = accO[mi][nj];                                         \
        const float wl = wL[nj], wr = wR[nj];                                 \
        uint32_t lo = (uint32_t)f2bf_bits((e[0] + o[0]) * wl) |               \
                      ((uint32_t)f2bf_bits((e[1] + o[1]) * wl) << 16);        \
        uint32_t hi = (uint32_t)f2bf_bits((e[2] + o[2]) * wl) |               \
                      ((uint32_t)f2bf_bits((e[3] + o[3]) * wl) << 16);        \
        *(uint32_t*)(sF + colL * 72 + ((q4 * 2) ^ swzL))       = lo;          \
        *(uint32_t*)(sF + colL * 72 + (((q4 + 2) * 2) ^ swzL)) = hi;          \
        lo = (uint32_t)f2bf_bits((e[0] - o[0]) * wr) |                        \
             ((uint32_t)f2bf_bits((e[1] - o[1]) * wr) << 16);                 \
        hi = (uint32_t)f2bf_bits((e[2] - o[2]) * wr) |                        \
             ((uint32_t)f2bf_bits((e[3] - o[3]) * wr) << 16);                 \
        *(uint32_t*)(sF + colR * 72 + ((q4 * 2) ^ swzR))       = lo;          \
        *(uint32_t*)(sF + colR * 72 + (((q4 + 2) * 2) ^ swzR)) = hi;          \
      }                                                                       \
    }                                                                         \
  }

  // stage group 0 (frames 0..31 = waves wm==0)
  if (wm == 0) STAGE_PASS();
  __syncthreads();
  // OLA chunks 1..31 (frames cl-1, cl both in group 0)
#pragma unroll 1
  for (int i = tid; i < 31 * 256; i += 512) {
    const int cl = 1 + (i >> 8);
    const int r  = i & 255;
    const float v0 = rd_sf(sF, 256 + r, cl - 1);
    const float v1 = rd_sf(sF, r, cl);
    outb[(t0 + cl) * 256 + r] = (v0 + v1) * invd;
  }
  if (ib == 0 && tid < 256) {  // chunk 0: only frame 0, n=r, denorm=win[r]^2
    const float w = win[tid];
    outb[tid] = rd_sf(sF, tid, 0) / (w * w + EPS_F);
  }
  // carry frame 31's upper half for the straddling chunk 32
  const float vsave = (tid < 256) ? rd_sf(sF, 256 + tid, 31) : 0.0f;
  __syncthreads();
  // stage group 1 (frames 32..63 = waves wm==1)
  if (wm == 1) STAGE_PASS();
  __syncthreads();
  if (tid < 256)  // chunk 32: frame 31 (saved) + frame 32 (row2=0)
    outb[(t0 + 32) * 256 + tid] = (vsave + rd_sf(sF, tid, 0)) * invd;
  // OLA chunks 33..63 (frames cl-1, cl in group 1; row2 = frame - 32)
#pragma unroll 1
  for (int i = tid; i < 31 * 256; i += 512) {
    const int cl = 33 + (i >> 8);
    const int r  = i & 255;
    const float v0 = rd_sf(sF, 256 + r, cl - 33);
    const float v1 = rd_sf(sF, r, cl - 32);
    outb[(t0 + cl) * 256 + r] = (v0 + v1) * invd;
  }
  if (ib == 63 && tid < 256) {  // chunk 4000: only frame 3999, n=256+r
    const float w = win[256 + tid];
    outb[1024000 + tid] = rd_sf(sF, 256 + tid, 31) / (w * w + EPS_F);
  }
}

extern "C" void kernel_launch(void* const* d_in, const int* in_sizes, int n_in,
                              void* d_out, int out_size, void* d_ws, size_t ws_size,
                              hipStream_t stream) {
  (void)in_sizes; (void)n_in; (void)out_size; (void)ws_size;
  const float2* tr = (const float2*)d_in[0];
  const float* win = (const float*)d_in[1];
  uint8_t* tb = (uint8_t*)d_ws;  // 68 * 256 * 16 = 278528 bytes
  build_table_kernel<<<dim3(544), dim3(256), 0, stream>>>(tb);
  istft_fused_kernel<<<dim3(64, 16), dim3(512), 0, stream>>>(tr, win, tb,
                                                             (float*)d_out);
}

// Round 13
// 55.391 us; speedup vs baseline: 1.7162x; 1.0252x over previous
//
#include <hip/hip_runtime.h>
#include <stdint.h>

// iSTFT as fused bf16-MFMA GEMM + overlap-add, with even/odd frequency fold.
//   frames[m][n]     = win[n]     * (E[m][n] + O[m][n])      n in [0,256)
//   frames[m][n+256] = win[n+256] * (E[m][n] - O[m][n])
//   E = even f (K=258 -> 9 steps of 32), O = odd f (K=256 -> 8 steps)
// R13 = R12 with the A-path cost moved off the LDS/VALU issue pipes.
// R12 counters: LDS-read issue ~70% of step time (8 ds_read_b64 A-frags +
// 4 ds_read_b128 B per wave-step) + 16 in-loop cvt VALU. Fix (T14 style):
//  - A staged via REGISTERS: lane loads 2x dwordx2 (f^=2w,2w+1 @ t=lane),
//    cvt f32->bf16 AT STAGE TIME, one ds_write_b64 into a [t][k] bf16 tile,
//    pitch 80B (5x16 -> b128-aligned reads; write = 4-way bank, ~1.6x, ok).
//  - A fragment read collapses to ONE ds_read_b128 per mi (k=g*8..g*8+7 =
//    re/im pairs of f^=g*4..+3, exact MFMA A order). 12 -> 6 LDS reads,
//    -16 VALU per wave-step; A LDS 32KB -> 10KB (total 43008B).
//  - ladder (prologue AL0,B0,AL1; per step: issue B(ks+1), AL(ks+2), then
//    late vmcnt(4) -> cvt -> ds_write A(ks+1)): stage-1 wait = vmcnt(2)
//    lgkmcnt(0) + s_barrier (retires B(ks), keeps AL(ks+1) in flight).
//    ks==15: stage-5 vmcnt(2); ks==16: stage-1 vmcnt(0). WAR/RAW contract
//    identical to the R5/R12-proven pattern.

#define EPS_F 1.1920928955078125e-07f
#define TWO_PI_OVER_512 1.2271846303085130e-02f

typedef __bf16 bf16x8 __attribute__((ext_vector_type(8)));
typedef float f32x4 __attribute__((ext_vector_type(4)));
typedef uint32_t u32x2 __attribute__((ext_vector_type(2)));

__device__ __forceinline__ uint16_t f2bf_bits(float x) {
  return __builtin_bit_cast(uint16_t, (__bf16)x);
}
__device__ __forceinline__ float bf2f_bits(uint16_t u) {
  return (float)__builtin_bit_cast(__bf16, u);
}

#define GLOAD16(srcp, dstp)                                                   \
  __builtin_amdgcn_global_load_lds(                                          \
      (const __attribute__((address_space(1))) uint32_t*)(srcp),             \
      (__attribute__((address_space(3))) uint32_t*)(dstp), 16, 0, 0)

// Table: 544 rows x N=256 bf16. Rows 0..287 = even-f phase (k_e = 2*fe+c,
// f = 2*fe, fe<=128 valid, rest zero-pad); rows 288..543 = odd-f phase
// (k_o = 2*fo+c, f = 2*fo+1). Packed 16B units: unit u = (k>>3)*256 + n,
// byte = (u<<4 ^ ((g&3)<<5)) + (k&7)*2  (bank swizzle baked into global
// layout so global_load_lds tile copies are verbatim).
__global__ void build_table_kernel(uint8_t* __restrict__ tb) {
  const int k = blockIdx.x;        // 0..543
  const int g = k >> 3;
  const int n = threadIdx.x;       // 0..255
  float v = 0.0f;
  int f, c, valid;
  if (k < 288) {
    const int fe = k >> 1;
    c = k & 1; f = 2 * fe; valid = (fe <= 128);
  } else {
    const int ko = k - 288;
    c = ko & 1; f = 2 * (ko >> 1) + 1; valid = 1;
  }
  if (valid) {
    const float s = (f == 0 || f == 256) ? 1.0f : 2.0f;
    const int a = (f * n) & 511;   // exact angle reduction
    const float th = (float)a * TWO_PI_OVER_512;
    const float tr = c ? -sinf(th) : cosf(th);
    v = s * tr * (1.0f / 512.0f);
  }
  const int off = (((g * 256 + n) << 4) ^ ((g & 3) << 5)) + ((k & 7) << 1);
  *(uint16_t*)(tb + off) = f2bf_bits(v);
}

// epilogue frame buffer: 512 cols x 32 rows bf16, pitch 72B, swizzled
__device__ __forceinline__ float rd_sf(const uint8_t* sF, int col, int row2) {
  return bf2f_bits(*(const uint16_t*)(
      sF + col * 72 + ((row2 * 2) ^ (((col >> 4) & 3) << 2))));
}

// One block: batch b, 64 consecutive frames [t0, t0+64), full N=512.
// Owns output chunks [t0+1, t0+63] (+ chunk 0 / chunk 4000 at the ends).
__global__ __launch_bounds__(512, 4)
void istft_fused_kernel(const float2* __restrict__ in,   // [B*257*4000] (re,im)
                        const float* __restrict__ win,   // [512]
                        const uint8_t* __restrict__ tb,  // packed table
                        float* __restrict__ out) {
  __shared__ __align__(1024) uint8_t smem[43008];
  uint8_t* sA = smem;            // A dbuf: 2 x (64 t x 80B), bf16 [t][k]
  uint8_t* sB = smem + 10240;    // B dbuf: 2 x 16KB
  uint8_t* sF = smem;            // epilogue alias: 512 cols x 72B = 36864B

  const int tid  = threadIdx.x;
  const int lane = tid & 63;
  const int wave = tid >> 6;       // 0..7
  const int wn   = wave & 3;       // N-quarter of the folded 256
  const int wm   = wave >> 2;      // M-half
  const int l15  = lane & 15;
  const int g    = lane >> 4;      // k-group within fragment
  const int b  = blockIdx.y;
  const int ib = blockIdx.x;       // 0..63
  const int t0 = (ib == 63) ? 3936 : ib * 63;

  f32x4 accE[2][4], accO[2][4];
#pragma unroll
  for (int mi = 0; mi < 2; ++mi)
#pragma unroll
    for (int nj = 0; nj < 4; ++nj) {
      accE[mi][nj] = (f32x4){0.f, 0.f, 0.f, 0.f};
      accO[mi][nj] = (f32x4){0.f, 0.f, 0.f, 0.f};
    }

  const long inBase = (long)b * (257L * 4000);
  const long tcol   = inBase + (t0 + lane);   // + f*4000

  float2 alq[2][2];  // A load queue: alq[KS&1][j] = input(f^=2w+j, t=lane)

  // f^ -> global f for step KS (compile-time under full unroll):
  //   KS<9  even phase: fe = KS*16+f^ (clamp 128; table rows beyond are 0)
  //   KS>=9 odd  phase: f = 2*((KS-9)*16+f^)+1
#define A_GLOBAL_F(KS, FH)                                                    \
  ((KS) < 9 ? 2 * ((((KS) * 16 + (FH)) > 128) ? 128 : ((KS) * 16 + (FH)))    \
            : 2 * (((KS) - 9) * 16 + (FH)) + 1)
#define ISSUE_AL(KS)                                                          \
  {                                                                           \
    const int fg0 = A_GLOBAL_F(KS, 2 * wave);                                 \
    const int fg1 = A_GLOBAL_F(KS, 2 * wave + 1);                             \
    alq[(KS) & 1][0] = in[tcol + (long)fg0 * 4000];                           \
    alq[(KS) & 1][1] = in[tcol + (long)fg1 * 4000];                           \
  }
  // cvt + one b64 write: k-quad 4w..4w+3 at t=lane, slot S
#define WRITE_A(KS)                                                           \
  {                                                                           \
    const float2 x = alq[(KS) & 1][0];                                        \
    const float2 y = alq[(KS) & 1][1];                                        \
    u32x2 wv;                                                                 \
    wv[0] = (uint32_t)f2bf_bits(x.x) | ((uint32_t)f2bf_bits(x.y) << 16);      \
    wv[1] = (uint32_t)f2bf_bits(y.x) | ((uint32_t)f2bf_bits(y.y) << 16);      \
    *(u32x2*)(sA + ((KS) & 1) * 5120 + lane * 80 + wave * 8) = wv;            \
  }
#define ISSUE_B(T)                                                            \
  {                                                                           \
    const uint8_t* src = tb + (T) * 16384 + wave * 2048 + lane * 16;          \
    uint8_t* dst = sB + ((T) & 1) * 16384 + wave * 2048 + lane * 16;          \
    GLOAD16(src, dst);                                                        \
    GLOAD16(src + 1024, dst + 1024);                                          \
  }
#define MFMA_STEP(ACC)                                                        \
  _Pragma("unroll") for (int nj = 0; nj < 4; ++nj) {                          \
    const bf16x8 bfr = *(const bf16x8*)(sBc + nbase + (nj << 8));             \
    ACC[0][nj] = __builtin_amdgcn_mfma_f32_16x16x32_bf16(af[0], bfr,          \
                                                         ACC[0][nj], 0, 0, 0);\
    ACC[1][nj] = __builtin_amdgcn_mfma_f32_16x16x32_bf16(af[1], bfr,          \
                                                         ACC[1][nj], 0, 0, 0);\
  }

  // ---- prologue: AL0(2), B0(2), AL1(2); retire AL0 (vmcnt 4), write A(0) --
  ISSUE_AL(0);
  __builtin_amdgcn_sched_barrier(0);
  ISSUE_B(0);
  __builtin_amdgcn_sched_barrier(0);
  ISSUE_AL(1);
  __builtin_amdgcn_sched_barrier(0);
  asm volatile("s_waitcnt vmcnt(4)" ::: "memory");
  WRITE_A(0);
  __builtin_amdgcn_sched_barrier(0);

  const int nbase = ((g * 256 + wn * 64 + l15) << 4) ^ (g << 5);

#pragma unroll
  for (int ks = 0; ks < 17; ++ks) {
    // stage 1: retire B(ks) (keep AL(ks+1) in flight); publish A/B slots
    if (ks < 16)
      asm volatile("s_waitcnt vmcnt(2) lgkmcnt(0)" ::: "memory");
    else
      asm volatile("s_waitcnt vmcnt(0) lgkmcnt(0)" ::: "memory");
    __builtin_amdgcn_s_barrier();
    __builtin_amdgcn_sched_barrier(0);

    // stage 2: B(ks+1) DMA into sB[(ks+1)&1] (read at ks-1; WAR-safe)
    if (ks < 16) {
      ISSUE_B(ks + 1);
    }
    __builtin_amdgcn_sched_barrier(0);
    // stage 3: A-loads for ks+2 into regs
    if (ks < 15) {
      ISSUE_AL(ks + 2);
    }
    __builtin_amdgcn_sched_barrier(0);

    // stage 4: fragments + MFMA
    const uint8_t* sAc = sA + (ks & 1) * 5120;
    bf16x8 af[2];
#pragma unroll
    for (int mi = 0; mi < 2; ++mi) {
      const int t = wm * 32 + mi * 16 + l15;
      af[mi] = *(const bf16x8*)(sAc + t * 80 + g * 16);
    }
    const uint8_t* sBc = sB + (ks & 1) * 16384;
    if (ks < 9) {
      MFMA_STEP(accE);
    } else {
      MFMA_STEP(accO);
    }
    __builtin_amdgcn_sched_barrier(0);

    // stage 5: retire AL(ks+1), cvt, ds_write into sA[(ks+1)&1]
    if (ks < 15) {
      asm volatile("s_waitcnt vmcnt(4)" ::: "memory");
      WRITE_A(ks + 1);
    } else if (ks == 15) {
      asm volatile("s_waitcnt vmcnt(2)" ::: "memory");
      WRITE_A(16);
    }
    __builtin_amdgcn_sched_barrier(0);
  }

  // ---- epilogue: two 32-frame passes through the 36KB swizzled buffer ----
  __syncthreads();  // all K-loop LDS reads done; smem becomes sF
  float* outb = out + (long)b * 1024256;
  const float invd = 1.0f / (1.0f + EPS_F);

  float wL[4], wR[4];
#pragma unroll
  for (int nj = 0; nj < 4; ++nj) {
    wL[nj] = win[wn * 64 + nj * 16 + l15];
    wR[nj] = win[wn * 64 + nj * 16 + l15 + 256];
  }

#define STAGE_PASS()                                                          \
  {                                                                           \
    _Pragma("unroll")                                                         \
    for (int mi = 0; mi < 2; ++mi) {                                          \
      const int q4 = mi * 16 + (g << 2); /* D row=(lane>>4)*4+r */            \
      _Pragma("unroll")                                                       \
      for (int nj = 0; nj < 4; ++nj) {                                        \
        const int colL = wn * 64 + nj * 16 + l15;                             \
        const int colR = colL + 256;                                          \
        const int swzL = ((colL >> 4) & 3) << 2;                              \
        const int swzR = ((colR >> 4) & 3) << 2;                              \
        const f32x4 e = accE[mi][nj];                                         \
        const f32x4 o = accO[mi][nj];                                         \
        const float wl = wL[nj], wr = wR[nj];                                 \
        uint32_t lo = (uint32_t)f2bf_bits((e[0] + o[0]) * wl) |               \
                      ((uint32_t)f2bf_bits((e[1] + o[1]) * wl) << 16);        \
        uint32_t hi = (uint32_t)f2bf_bits((e[2] + o[2]) * wl) |               \
                      ((uint32_t)f2bf_bits((e[3] + o[3]) * wl) << 16);        \
        *(uint32_t*)(sF + colL * 72 + ((q4 * 2) ^ swzL))       = lo;          \
        *(uint32_t*)(sF + colL * 72 + (((q4 + 2) * 2) ^ swzL)) = hi;          \
        lo = (uint32_t)f2bf_bits((e[0] - o[0]) * wr) |                        \
             ((uint32_t)f2bf_bits((e[1] - o[1]) * wr) << 16);                 \
        hi = (uint32_t)f2bf_bits((e[2] - o[2]) * wr) |                        \
             ((uint32_t)f2bf_bits((e[3] - o[3]) * wr) << 16);                 \
        *(uint32_t*)(sF + colR * 72 + ((q4 * 2) ^ swzR))       = lo;          \
        *(uint32_t*)(sF + colR * 72 + (((q4 + 2) * 2) ^ swzR)) = hi;          \
      }                                                                       \
    }                                                                         \
  }

  // stage group 0 (frames 0..31 = waves wm==0)
  if (wm == 0) STAGE_PASS();
  __syncthreads();
  // OLA chunks 1..31 (frames cl-1, cl both in group 0)
#pragma unroll 1
  for (int i = tid; i < 31 * 256; i += 512) {
    const int cl = 1 + (i >> 8);
    const int r  = i & 255;
    const float v0 = rd_sf(sF, 256 + r, cl - 1);
    const float v1 = rd_sf(sF, r, cl);
    outb[(t0 + cl) * 256 + r] = (v0 + v1) * invd;
  }
  if (ib == 0 && tid < 256) {  // chunk 0: only frame 0, n=r, denorm=win[r]^2
    const float w = win[tid];
    outb[tid] = rd_sf(sF, tid, 0) / (w * w + EPS_F);
  }
  // carry frame 31's upper half for the straddling chunk 32
  const float vsave = (tid < 256) ? rd_sf(sF, 256 + tid, 31) : 0.0f;
  __syncthreads();
  // stage group 1 (frames 32..63 = waves wm==1)
  if (wm == 1) STAGE_PASS();
  __syncthreads();
  if (tid < 256)  // chunk 32: frame 31 (saved) + frame 32 (row2=0)
    outb[(t0 + 32) * 256 + tid] = (vsave + rd_sf(sF, tid, 0)) * invd;
  // OLA chunks 33..63 (frames cl-1, cl in group 1; row2 = frame - 32)
#pragma unroll 1
  for (int i = tid; i < 31 * 256; i += 512) {
    const int cl = 33 + (i >> 8);
    const int r  = i & 255;
    const float v0 = rd_sf(sF, 256 + r, cl - 33);
    const float v1 = rd_sf(sF, r, cl - 32);
    outb[(t0 + cl) * 256 + r] = (v0 + v1) * invd;
  }
  if (ib == 63 && tid < 256) {  // chunk 4000: only frame 3999, n=256+r
    const float w = win[256 + tid];
    outb[1024000 + tid] = rd_sf(sF, 256 + tid, 31) / (w * w + EPS_F);
  }
}

extern "C" void kernel_launch(void* const* d_in, const int* in_sizes, int n_in,
                              void* d_out, int out_size, void* d_ws, size_t ws_size,
                              hipStream_t stream) {
  (void)in_sizes; (void)n_in; (void)out_size; (void)ws_size;
  const float2* tr = (const float2*)d_in[0];
  const float* win = (const float*)d_in[1];
  uint8_t* tb = (uint8_t*)d_ws;  // 68 * 256 * 16 = 278528 bytes
  build_table_kernel<<<dim3(544), dim3(256), 0, stream>>>(tb);
  istft_fused_kernel<<<dim3(64, 16), dim3(512), 0, stream>>>(tr, win, tb,
                                                             (float*)d_out);
}